// Round 19
// baseline (244.332 us; speedup 1.0000x reference)
//
#include <hip/hip_runtime.h>
#include <hip/hip_bf16.h>

// SelfAttention: B=2,S=2048,D=1024,H=16,E=64. Softmax over QUERY axis.
//   Qb = (x@wq)*C1, Kb = x@wk, Vt = (x@wv)^T          (m97-style staged GEMM)
//   stats: m_t = max_s d (FULL), l_t = sum_s 2^(d-m_t) (two-pass, s split over 4)
//   Vs = (1/l_t)*Vt ; attn: Hd[:, z*1024+..] = 2^(d-m) @ Vs   (keys split over 2)
//   out = Hd[4096][2048] @ WaT[1024][2048]             (staged GEMM, K=2048)
// R19: k_attn waves own 64 queries (was 32): K-frag ds_reads, ci loads, V-frag
//      loads and block-level K/V staging amortized 2x; grid 512, acc[4][4],
//      __launch_bounds__(256,2) (session rule: (256,4) pins 64 VGPR -> spill).
//      All other kernels frozen at R18 (measured-best base 239us).

typedef __attribute__((ext_vector_type(8))) short bf16x8;
typedef __attribute__((ext_vector_type(4))) float f32x4;

#define C1 0.18033688011112042f  // log2(e)/8

__device__ __forceinline__ unsigned short f2bf(float f){
  union { __hip_bfloat16 h; unsigned short u; } cv;
  cv.h = __float2bfloat16(f);
  return cv.u;
}
__device__ __forceinline__ unsigned int pk2(float a, float b){
  union { __hip_bfloat162 h; unsigned int u; } cv;
  cv.h = __float22bfloat162_rn(make_float2(a, b));
  return cv.u;
}
__device__ __forceinline__ unsigned long long pack4(float a, float b, float c, float d){
  return (unsigned long long)pk2(a, b) | ((unsigned long long)pk2(c, d) << 32);
}
__device__ __forceinline__ float bf2f(unsigned short u){
  unsigned int x = ((unsigned int)u) << 16;
  return __builtin_bit_cast(float, x);
}

// ---- lane-half / lane-16-group exchanges (gfx950 permlane*_swap, shfl fallback)
__device__ __forceinline__ void swap32(unsigned a, unsigned b, unsigned &x, unsigned &y){
#if __has_builtin(__builtin_amdgcn_permlane32_swap)
  auto r = __builtin_amdgcn_permlane32_swap(a, b, false, false);
  x = r[0]; y = r[1];
#else
  int lane = threadIdx.x & 63;
  unsigned as = __shfl_xor((int)a, 32), bs = __shfl_xor((int)b, 32);
  x = (lane & 32) ? bs : a;
  y = (lane & 32) ? b : as;
#endif
}
__device__ __forceinline__ void swap16(unsigned a, unsigned b, unsigned &x, unsigned &y){
#if __has_builtin(__builtin_amdgcn_permlane16_swap)
  auto r = __builtin_amdgcn_permlane16_swap(a, b, false, false);
  x = r[0]; y = r[1];
#else
  int lane = threadIdx.x & 63;
  unsigned as = __shfl_xor((int)a, 16), bs = __shfl_xor((int)b, 16);
  x = (lane & 16) ? bs : a;
  y = (lane & 16) ? b : as;
#endif
}

#define GLOAD16(SRC, DST)                                                        \
  __builtin_amdgcn_global_load_lds(                                              \
      (const __attribute__((address_space(1))) void*)(SRC),                      \
      (__attribute__((address_space(3))) void*)(DST), 16, 0, 0)

// ---------------- merged prep: x->bf16, w3 transpose, wagg transpose -----------
// flat grid 5120: [0,4096) cvt_x ; [4096,4864) w3t ; [4864,5120) waggt
__global__ __launch_bounds__(256) void k_prep(const float* __restrict__ x,
                                              const float* __restrict__ wq,
                                              const float* __restrict__ wk,
                                              const float* __restrict__ wv,
                                              const float* __restrict__ wagg,
                                              unsigned short* __restrict__ Xb,
                                              unsigned short* __restrict__ Wall,
                                              unsigned short* __restrict__ Wat){
  __shared__ unsigned short T[64][72];
  int bid = blockIdx.x;
  if (bid < 4096){
    int i = (bid * 256 + threadIdx.x) * 4;
    float4 v = *reinterpret_cast<const float4*>(x + i);
    *reinterpret_cast<unsigned long long*>(Xb + i) = pack4(v.x, v.y, v.z, v.w);
    return;
  }
  bid -= 4096;
  const int r = threadIdx.x >> 2, c0 = (threadIdx.x & 3) << 4;
  if (bid < 768){
    const int z = bid >> 8, rem = bid & 255, hy = rem >> 4, dt = rem & 15;
    const float* w = ((z == 0) ? wq : ((z == 1) ? wk : wv)) + ((size_t)hy << 16);
    const int d0 = dt * 64;
    const float* src = w + ((size_t)(d0 + r) << 6) + c0;
#pragma unroll
    for (int i = 0; i < 4; ++i){
      float4 v = *(const float4*)(src + 4 * i);
      T[r][c0 + 4 * i + 0] = f2bf(v.x);
      T[r][c0 + 4 * i + 1] = f2bf(v.y);
      T[r][c0 + 4 * i + 2] = f2bf(v.z);
      T[r][c0 + 4 * i + 3] = f2bf(v.w);
    }
    __syncthreads();
    const int e = threadIdx.x >> 2, k0 = (threadIdx.x & 3) << 4;
    union { unsigned short s[8]; bf16x8 v; } u0, u1;
#pragma unroll
    for (int k = 0; k < 8; ++k){ u0.s[k] = T[k0 + k][e]; u1.s[k] = T[k0 + 8 + k][e]; }
    unsigned short* dst = Wall + ((size_t)z << 20) + (((size_t)hy * 64 + e) << 10) + d0 + k0;
    *(bf16x8*)dst = u0.v;
    *(bf16x8*)(dst + 8) = u1.v;
    return;
  }
  bid -= 768;
  {
    const int het = bid >> 4, dt = bid & 15;
    const int d0 = dt * 64, he0 = het * 64;
    const float* src = wagg + ((size_t)(he0 + r) << 10) + d0 + c0;
#pragma unroll
    for (int i = 0; i < 4; ++i){
      float4 v = *(const float4*)(src + 4 * i);
      T[r][c0 + 4 * i + 0] = f2bf(v.x);
      T[r][c0 + 4 * i + 1] = f2bf(v.y);
      T[r][c0 + 4 * i + 2] = f2bf(v.z);
      T[r][c0 + 4 * i + 3] = f2bf(v.w);
    }
    __syncthreads();
    const int d = threadIdx.x >> 2, k0 = (threadIdx.x & 3) << 4;
    union { unsigned short s[8]; bf16x8 v; } u0, u1;
#pragma unroll
    for (int k = 0; k < 8; ++k){ u0.s[k] = T[k0 + k][d]; u1.s[k] = T[k0 + 8 + k][d]; }
    unsigned short* dst = Wat + ((size_t)(d0 + d) << 11) + he0 + k0;
    *(bf16x8*)dst = u0.v;
    *(bf16x8*)(dst + 8) = u1.v;
    *(bf16x8*)(dst + 1024) = u0.v;
    *(bf16x8*)(dst + 1032) = u1.v;
  }
}

// ---------------- staged GEMM: projections ----------------
__global__ __launch_bounds__(256) void k_proj(const unsigned short* __restrict__ Wall,
                                              const unsigned short* __restrict__ Xb,
                                              unsigned short* __restrict__ Qb,
                                              unsigned short* __restrict__ Kb,
                                              unsigned short* __restrict__ Vt){
  __shared__ __align__(16) unsigned short lds[2][2][4096];
  const int z = blockIdx.z;
  const unsigned short* Wt = Wall + ((size_t)z << 20);
  const int t = threadIdx.x;
  const int w = t >> 6, lane = t & 63, g = lane >> 4, cl = lane & 15;
  const int wn = w >> 1, wm = w & 1;
  const int n0 = blockIdx.x * 128, m0 = blockIdx.y * 128;

  const int rowS = t & 127;
  const unsigned short* sA = Wt + (size_t)(n0 + rowS) * 1024 + (t >> 7) * 8;
  const unsigned short* sB = Xb + (size_t)(m0 + rowS) * 1024 + (t >> 7) * 8;

  f32x4 acc[4][4];
#pragma unroll
  for (int i = 0; i < 4; ++i)
#pragma unroll
    for (int j = 0; j < 4; ++j) acc[i][j] = f32x4{0.f, 0.f, 0.f, 0.f};

  GLOAD16(sA,      &lds[0][0][t * 8]);
  GLOAD16(sA + 16, &lds[0][0][t * 8 + 2048]);
  GLOAD16(sB,      &lds[0][1][t * 8]);
  GLOAD16(sB + 16, &lds[0][1][t * 8 + 2048]);
  __syncthreads();

#pragma unroll 2
  for (int kt = 0; kt < 32; ++kt){
    const int cur = kt & 1;
    if (kt < 31){
      const unsigned short* nA = sA + (kt + 1) * 32;
      const unsigned short* nB = sB + (kt + 1) * 32;
      GLOAD16(nA,      &lds[cur ^ 1][0][t * 8]);
      GLOAD16(nA + 16, &lds[cur ^ 1][0][t * 8 + 2048]);
      GLOAD16(nB,      &lds[cur ^ 1][1][t * 8]);
      GLOAD16(nB + 16, &lds[cur ^ 1][1][t * 8 + 2048]);
    }
    const unsigned short* la = &lds[cur][0][g * 1024];
    const unsigned short* lb = &lds[cur][1][g * 1024];
    bf16x8 af[4], bq[4];
#pragma unroll
    for (int i = 0; i < 4; ++i) af[i] = *(const bf16x8*)(la + (wn * 64 + i * 16 + cl) * 8);
#pragma unroll
    for (int j = 0; j < 4; ++j) bq[j] = *(const bf16x8*)(lb + (wm * 64 + j * 16 + cl) * 8);
#pragma unroll
    for (int i = 0; i < 4; ++i)
#pragma unroll
      for (int j = 0; j < 4; ++j)
        acc[i][j] = __builtin_amdgcn_mfma_f32_16x16x32_bf16(af[i], bq[j], acc[i][j], 0, 0, 0);
    __syncthreads();
  }

  const float scale = (z == 0) ? C1 : 1.f;
#pragma unroll
  for (int i = 0; i < 4; ++i)
#pragma unroll
    for (int j = 0; j < 4; ++j)
#pragma unroll
      for (int jj = 0; jj < 4; ++jj) acc[i][j][jj] *= scale;

  if (z < 2){
    unsigned short* outp = (z == 0) ? Qb : Kb;
#pragma unroll
    for (int i = 0; i < 4; ++i)
#pragma unroll
      for (int j = 0; j < 4; ++j){
        int m = m0 + wm * 64 + 16 * j + cl;
        int n = n0 + wn * 64 + 16 * i + 4 * g;
        *reinterpret_cast<unsigned long long*>(outp + (size_t)m * 1024 + n) =
            pack4(acc[i][j][0], acc[i][j][1], acc[i][j][2], acc[i][j][3]);
      }
  } else {
    int b = m0 >> 11;
#pragma unroll
    for (int i = 0; i < 4; ++i)
#pragma unroll
      for (int j = 0; j < 4; ++j){
        int c2 = (m0 & 2047) + wm * 64 + 16 * j + cl;
        int nb = b * 1024 + n0 + wn * 64 + 16 * i + 4 * g;
#pragma unroll
        for (int jj = 0; jj < 4; ++jj)
          Vt[(size_t)(nb + jj) * 2048 + c2] = f2bf(acc[i][j][jj]);
      }
  }
}

// ---------------- staged GEMM: output projection (128m x 64n, 512 blocks) ------
__global__ __launch_bounds__(256) void k_agg(const unsigned short* __restrict__ Wa,
                                             const unsigned short* __restrict__ Hd,
                                             float* __restrict__ outp){
  __shared__ __align__(16) unsigned short lds[2][6144];  // A[4][64][8] | B[4][128][8]
  const int t = threadIdx.x;
  const int w = t >> 6, lane = t & 63, g = lane >> 4, cl = lane & 15;
  const int wn = w >> 1, wm = w & 1;
  const int n0 = blockIdx.x * 64, m0 = blockIdx.y * 128;

  const unsigned short* sA  = Wa + (size_t)(n0 + (t & 63)) * 2048 + (t >> 6) * 8;
  const unsigned short* sB1 = Hd + (size_t)(m0 + (t & 127)) * 2048 + (t >> 7) * 8;
  unsigned short* dA0  = &lds[0][0]    + t * 8;
  unsigned short* dB10 = &lds[0][2048] + t * 8;

  f32x4 acc[2][4];
#pragma unroll
  for (int j = 0; j < 2; ++j)
#pragma unroll
    for (int i = 0; i < 4; ++i) acc[j][i] = f32x4{0.f, 0.f, 0.f, 0.f};

  GLOAD16(sA,       dA0);
  GLOAD16(sB1,      dB10);
  GLOAD16(sB1 + 16, dB10 + 2048);
  __syncthreads();

#pragma unroll 2
  for (int kt = 0; kt < 64; ++kt){
    const int cur = kt & 1;
    if (kt < 63){
      const unsigned short* nA = sA  + (kt + 1) * 32;
      const unsigned short* nB = sB1 + (kt + 1) * 32;
      GLOAD16(nA,      dA0  + (cur ^ 1) * 6144);
      GLOAD16(nB,      dB10 + (cur ^ 1) * 6144);
      GLOAD16(nB + 16, dB10 + (cur ^ 1) * 6144 + 2048);
    }
    const unsigned short* la = &lds[cur][0];
    const unsigned short* lb = &lds[cur][2048];
    bf16x8 af[2], bq[4];
#pragma unroll
    for (int j = 0; j < 2; ++j) af[j] = *(const bf16x8*)(la + g * 512 + (wn * 32 + j * 16 + cl) * 8);
#pragma unroll
    for (int i = 0; i < 4; ++i) bq[i] = *(const bf16x8*)(lb + g * 1024 + (wm * 64 + i * 16 + cl) * 8);
#pragma unroll
    for (int j = 0; j < 2; ++j)
#pragma unroll
      for (int i = 0; i < 4; ++i)
        acc[j][i] = __builtin_amdgcn_mfma_f32_16x16x32_bf16(af[j], bq[i], acc[j][i], 0, 0, 0);
    __syncthreads();
  }
#pragma unroll
  for (int j = 0; j < 2; ++j)
#pragma unroll
    for (int i = 0; i < 4; ++i){
      int m = m0 + wm * 64 + 16 * i + cl;
      int n = n0 + wn * 32 + 16 * j + 4 * g;
      *reinterpret_cast<f32x4*>(outp + (size_t)m * 1024 + n) = acc[j][i];
    }
}

// ---------------- stats: LDS-staged Q, two-pass FULL max, s split over 4 --------
__global__ __launch_bounds__(256, 4) void k_stats(const unsigned short* __restrict__ Qb,
                                                  const unsigned short* __restrict__ Kb,
                                                  float* __restrict__ mp,
                                                  float* __restrict__ lp){
  __shared__ __align__(16) unsigned short Qs[2][64][64];
  const int B = blockIdx.x;
  const int xcd = B & 7, rest = B >> 3;
  const int tx = rest & 7, gi = rest >> 3;
  const int grp = xcd + 8 * gi;
  const int bh = grp & 31, z = grp >> 5;
  const int b = bh >> 4, h = bh & 15;
  const int w = threadIdx.x >> 6, lane = threadIdx.x & 63;
  const int g = lane >> 4, cl = lane & 15;
  const int t0 = tx * 256 + w * 64;

  const unsigned short* kp = Kb + (size_t)(b * 2048 + t0 + cl) * 1024 + h * 64 + g * 8;
  bf16x8 a[4][2];
#pragma unroll
  for (int ti = 0; ti < 4; ++ti){
    a[ti][0] = *(const bf16x8*)(kp + (size_t)ti * 16 * 1024);
    a[ti][1] = *(const bf16x8*)(kp + (size_t)ti * 16 * 1024 + 32);
  }

  const int r0 = threadIdx.x >> 3, sl = threadIdx.x & 7;
  const unsigned short* qsrc = Qb + (size_t)(b * 2048 + z * 512 + r0) * 1024 + h * 64
                               + ((sl ^ (r0 & 7)) * 8);
  unsigned short* qdst0 = &Qs[0][0][0] + threadIdx.x * 8;

  const int e0 = (g ^ (cl & 7)) * 8;
  const int e1 = ((g + 4) ^ (cl & 7)) * 8;

  float m[16], l[16];
#pragma unroll
  for (int i = 0; i < 16; ++i){ m[i] = -3.0e38f; l[i] = 0.f; }

  // ---- pass 1: max ----
  GLOAD16(qsrc,             qdst0);
  GLOAD16(qsrc + 32 * 1024, qdst0 + 2048);
  __syncthreads();
  for (int c = 0; c < 8; ++c){
    const int buf = c & 1;
    if (c < 7){
      const unsigned short* s2 = qsrc + (size_t)(c + 1) * 64 * 1024;
      unsigned short* d2 = qdst0 + (buf ^ 1) * 4096;
      GLOAD16(s2,             d2);
      GLOAD16(s2 + 32 * 1024, d2 + 2048);
    }
#pragma unroll
    for (int st = 0; st < 4; ++st){
      const unsigned short* qrow = &Qs[buf][st * 16 + cl][0];
      bf16x8 b0 = *(const bf16x8*)(qrow + e0);
      bf16x8 b1 = *(const bf16x8*)(qrow + e1);
#pragma unroll
      for (int ti = 0; ti < 4; ++ti){
        f32x4 zz = {0.f, 0.f, 0.f, 0.f};
        f32x4 d = __builtin_amdgcn_mfma_f32_16x16x32_bf16(a[ti][0], b0, zz, 0, 0, 0);
        d = __builtin_amdgcn_mfma_f32_16x16x32_bf16(a[ti][1], b1, d, 0, 0, 0);
#pragma unroll
        for (int j = 0; j < 4; ++j) m[ti * 4 + j] = fmaxf(m[ti * 4 + j], d[j]);
      }
    }
    __syncthreads();
  }
#pragma unroll
  for (int off = 1; off < 16; off <<= 1)
#pragma unroll
    for (int i = 0; i < 16; ++i) m[i] = fmaxf(m[i], __shfl_xor(m[i], off));

  // ---- pass 2: sum of 2^(d-m) (zero-C, explicit subtract) ----
  GLOAD16(qsrc,             qdst0);
  GLOAD16(qsrc + 32 * 1024, qdst0 + 2048);
  __syncthreads();
  for (int c = 0; c < 8; ++c){
    const int buf = c & 1;
    if (c < 7){
      const unsigned short* s2 = qsrc + (size_t)(c + 1) * 64 * 1024;
      unsigned short* d2 = qdst0 + (buf ^ 1) * 4096;
      GLOAD16(s2,             d2);
      GLOAD16(s2 + 32 * 1024, d2 + 2048);
    }
#pragma unroll
    for (int st = 0; st < 4; ++st){
      const unsigned short* qrow = &Qs[buf][st * 16 + cl][0];
      bf16x8 b0 = *(const bf16x8*)(qrow + e0);
      bf16x8 b1 = *(const bf16x8*)(qrow + e1);
#pragma unroll
      for (int ti = 0; ti < 4; ++ti){
        f32x4 zz = {0.f, 0.f, 0.f, 0.f};
        f32x4 d = __builtin_amdgcn_mfma_f32_16x16x32_bf16(a[ti][0], b0, zz, 0, 0, 0);
        d = __builtin_amdgcn_mfma_f32_16x16x32_bf16(a[ti][1], b1, d, 0, 0, 0);
#pragma unroll
        for (int j = 0; j < 4; ++j) l[ti * 4 + j] += exp2f(d[j] - m[ti * 4 + j]);
      }
    }
    __syncthreads();
  }
#pragma unroll
  for (int off = 1; off < 16; off <<= 1)
#pragma unroll
    for (int i = 0; i < 16; ++i) l[i] += __shfl_xor(l[i], off);

  if (cl == 0){
    size_t base = ((size_t)z * 32 + bh) * 2048 + t0;
#pragma unroll
    for (int ti = 0; ti < 4; ++ti){
      f32x4 mv = {m[ti * 4 + 0], m[ti * 4 + 1], m[ti * 4 + 2], m[ti * 4 + 3]};
      f32x4 lv = {l[ti * 4 + 0], l[ti * 4 + 1], l[ti * 4 + 2], l[ti * 4 + 3]};
      *(f32x4*)(mp + base + ti * 16 + 4 * g) = mv;
      *(f32x4*)(lp + base + ti * 16 + 4 * g) = lv;
    }
  }
}

// combine the four s-quarter partials -> m2 (final max), rl (1/l)
__global__ void k_mcomb(const float* __restrict__ mp, const float* __restrict__ lp,
                        float* __restrict__ m2, float* __restrict__ rl){
  int i = blockIdx.x * 256 + threadIdx.x;   // 65536
  float m0 = mp[i], m1 = mp[65536 + i], m2v = mp[131072 + i], m3 = mp[196608 + i];
  float l0 = lp[i], l1 = lp[65536 + i], l2 = lp[131072 + i], l3 = lp[196608 + i];
  float m = fmaxf(fmaxf(m0, m1), fmaxf(m2v, m3));
  float l = l0 * exp2f(m0 - m) + l1 * exp2f(m1 - m)
          + l2 * exp2f(m2v - m) + l3 * exp2f(m3 - m);
  m2[i] = m;
  rl[i] = 1.f / l;
}

// Vs[t,e] = rl[t] * V[t,e], in-place on Vt [b*1024+he][2048]
__global__ void k_scale_v(unsigned short* __restrict__ Vt, const float* __restrict__ rl){
  int row = blockIdx.x;
  int b = row >> 10, h = (row >> 6) & 15;
  int t = threadIdx.x * 8;
  const float* r = rl + (size_t)(b * 16 + h) * 2048 + t;
  unsigned short* p = Vt + (size_t)row * 2048 + t;
  bf16x8 v = *(const bf16x8*)p;
  f32x4 r0 = *(const f32x4*)r;
  f32x4 r1 = *(const f32x4*)(r + 4);
  float f[8];
#pragma unroll
  for (int j = 0; j < 8; ++j) f[j] = bf2f((unsigned short)v[j]);
#pragma unroll
  for (int j = 0; j < 4; ++j){ f[j] *= r0[j]; f[4 + j] *= r1[j]; }
  unsigned long long* q = (unsigned long long*)p;
  q[0] = pack4(f[0], f[1], f[2], f[3]);
  q[1] = pack4(f[4], f[5], f[6], f[7]);
}

// ---------------- attention: 64 queries/wave, 64-key chunks, P in registers ----
// grid 512 flat (3|3|3 bits = xcd|sx|gi): 8 sx x (32 bh x 2 z); block = 256 q.
__global__ __launch_bounds__(256, 2) void k_attn(const unsigned short* __restrict__ Qb,
                                                 const unsigned short* __restrict__ Kb,
                                                 const unsigned short* __restrict__ Vt,
                                                 const float* __restrict__ m2,
                                                 unsigned short* __restrict__ Hd){
  __shared__ __align__(16) unsigned short KsL[2 * 64 * 64];  // 16 KB: [key][e]
  __shared__ __align__(16) unsigned short VsL[2 * 64 * 64];  // 16 KB: [e][t-chunk]
  __shared__ __align__(16) float Ms[1024];                   //  4 KB: NEGATED m2
  const int B = blockIdx.x;
  const int xcd = B & 7, rest = B >> 3;
  const int sx = rest & 7, gi = rest >> 3;          // sx 0..7, gi 0..7
  const int grp = xcd + 8 * gi;                     // 0..63 = bh + 32*z
  const int bh = grp & 31, z = grp >> 5;            // z 0..1
  const int b = bh >> 4, h = bh & 15;
  const int lane = threadIdx.x & 63;
  const int g = lane >> 4, cl = lane & 15;
  const int s0w = sx * 256 + (threadIdx.x >> 6) * 64;
  const int tbase = z * 1024;

  // stage NEGATED m2 slice for this (bh, z): used directly as MFMA C-init
  {
    int i = threadIdx.x * 4;
    f32x4 mv = *(const f32x4*)(m2 + (size_t)bh * 2048 + tbase + i);
    *(f32x4*)&Ms[i] = f32x4{-mv[0], -mv[1], -mv[2], -mv[3]};
  }

  bf16x8 q[4][2];
#pragma unroll
  for (int ss = 0; ss < 4; ++ss){
    const unsigned short* qp = Qb + (size_t)(b * 2048 + s0w + ss * 16 + cl) * 1024 + h * 64 + g * 8;
    q[ss][0] = *(const bf16x8*)(qp);
    q[ss][1] = *(const bf16x8*)(qp + 32);
  }
  f32x4 acc[4][4];
#pragma unroll
  for (int i = 0; i < 4; ++i)
#pragma unroll
    for (int ss = 0; ss < 4; ++ss) acc[i][ss] = f32x4{0.f, 0.f, 0.f, 0.f};

  const int srow = threadIdx.x >> 3;
  const int sseg = ((threadIdx.x & 7) ^ (srow & 7)) * 8;
  const unsigned short* kStage = Kb + (size_t)(b * 2048 + tbase + srow) * 1024 + h * 64 + sseg;
  const unsigned short* vStage = Vt + (size_t)(b * 1024 + h * 64 + srow) * 2048 + tbase + sseg;
  unsigned short* kDst = &KsL[0] + threadIdx.x * 8;
  unsigned short* vDst = &VsL[0] + threadIdx.x * 8;

  const int eK = (g ^ (cl & 7)) * 8;
  const int eK2 = ((g + 4) ^ (cl & 7)) * 8;

#define ASTAGE(c, buf) {                                                          \
    const unsigned short* ks_ = kStage + (size_t)(c) * 64 * 1024;                 \
    const unsigned short* vs_ = vStage + (c) * 64;                                \
    unsigned short* kd_ = kDst + (buf) * 4096;                                    \
    unsigned short* vd_ = vDst + (buf) * 4096;                                    \
    GLOAD16(ks_,             kd_);                                                \
    GLOAD16(ks_ + 32 * 1024, kd_ + 2048);                                         \
    GLOAD16(vs_,             vd_);                                                \
    GLOAD16(vs_ + (size_t)32 * 2048, vd_ + 2048); }

  ASTAGE(0, 0);
  __syncthreads();

  for (int c = 0; c < 16; ++c){
    const int buf = c & 1;
    if (c < 15) ASTAGE(c + 1, buf ^ 1);
    const unsigned short* Kbuf = &KsL[0] + buf * 4096;
    const unsigned short* Vbuf = &VsL[0] + buf * 4096;
#pragma unroll
    for (int sc = 0; sc < 2; ++sc){
      const unsigned short* kr0 = Kbuf + (sc * 32 + cl) * 64;
      const unsigned short* kr1 = Kbuf + (sc * 32 + 16 + cl) * 64;
      bf16x8 a00 = *(const bf16x8*)(kr0 + eK);
      bf16x8 a01 = *(const bf16x8*)(kr0 + eK2);
      bf16x8 a10 = *(const bf16x8*)(kr1 + eK);
      bf16x8 a11 = *(const bf16x8*)(kr1 + eK2);
      f32x4 ci0 = *(const f32x4*)&Ms[c * 64 + sc * 32 + 4 * g];        // = -m
      f32x4 ci1 = *(const f32x4*)&Ms[c * 64 + sc * 32 + 16 + 4 * g];   // = -m

      bf16x8 pb[4];
#pragma unroll
      for (int ss = 0; ss < 4; ++ss){
        __builtin_amdgcn_s_setprio(1);
        f32x4 d0 = __builtin_amdgcn_mfma_f32_16x16x32_bf16(a00, q[ss][0], ci0, 0, 0, 0);
        d0 = __builtin_amdgcn_mfma_f32_16x16x32_bf16(a01, q[ss][1], d0, 0, 0, 0);
        f32x4 d1 = __builtin_amdgcn_mfma_f32_16x16x32_bf16(a10, q[ss][0], ci1, 0, 0, 0);
        d1 = __builtin_amdgcn_mfma_f32_16x16x32_bf16(a11, q[ss][1], d1, 0, 0, 0);
        __builtin_amdgcn_s_setprio(0);
        unsigned w00 = pk2(exp2f(d0[0]), exp2f(d0[1]));
        unsigned w01 = pk2(exp2f(d0[2]), exp2f(d0[3]));
        unsigned w10 = pk2(exp2f(d1[0]), exp2f(d1[1]));
        unsigned w11 = pk2(exp2f(d1[2]), exp2f(d1[3]));
        unsigned sa0, sb0, sa1, sb1, W0, W1, W2, W3;
        swap32(w00, w10, sa0, sb0);
        swap32(w01, w11, sa1, sb1);
        swap16(sa0, sb0, W0, W2);
        swap16(sa1, sb1, W1, W3);
        union { unsigned u[4]; bf16x8 v; } fr;
        fr.u[0] = W0; fr.u[1] = W1; fr.u[2] = W2; fr.u[3] = W3;
        pb[ss] = fr.v;
      }
      __builtin_amdgcn_s_setprio(1);
#pragma unroll
      for (int i = 0; i < 4; ++i){
        bf16x8 av = *(const bf16x8*)(Vbuf + (16 * i + cl) * 64 + ((sc * 4 + g) ^ (cl & 7)) * 8);
#pragma unroll
        for (int ss = 0; ss < 4; ++ss)
          acc[i][ss] = __builtin_amdgcn_mfma_f32_16x16x32_bf16(av, pb[ss], acc[i][ss], 0, 0, 0);
      }
      __builtin_amdgcn_s_setprio(0);
    }
    __syncthreads();
  }
#undef ASTAGE
#pragma unroll
  for (int i = 0; i < 4; ++i)
#pragma unroll
    for (int ss = 0; ss < 4; ++ss){
      *reinterpret_cast<unsigned long long*>(
          Hd + (size_t)(b * 2048 + s0w + ss * 16 + cl) * 2048 + z * 1024 + h * 64 + 16 * i + 4 * g) =
          pack4(acc[i][ss][0], acc[i][ss][1], acc[i][ss][2], acc[i][ss][3]);
    }
}

extern "C" void kernel_launch(void* const* d_in, const int* in_sizes, int n_in,
                              void* d_out, int out_size, void* d_ws, size_t ws_size,
                              hipStream_t stream) {
  const float* x    = (const float*)d_in[0];
  const float* wq   = (const float*)d_in[2];
  const float* wk   = (const float*)d_in[3];
  const float* wv   = (const float*)d_in[4];
  const float* wagg = (const float*)d_in[5];
  float* outp = (float*)d_out;

  char* ws = (char*)d_ws;
  unsigned short* Xb  = (unsigned short*)(ws);                 // 8MB, dead after k_proj
  unsigned short* Hd  = (unsigned short*)(ws);                 // 16MB [4096][2048]
  unsigned short* Wall= (unsigned short*)(ws + 16777216);      // 6MB, dead after k_proj
  float* mp = (float*)(ws + 16777216);                         // 1 MB [4][32][2048]
  float* lp = (float*)(ws + 17825792);                         // 1 MB
  float* m2 = (float*)(ws + 18874368);                         // 256 KB
  float* rl = (float*)(ws + 19136512);                         // 256 KB
  unsigned short* Wat = (unsigned short*)(ws + 23068672);      // 4 MB [d][2048]
  unsigned short* Qb  = (unsigned short*)(ws + 27262976);      // 8 MB (pre-scaled by C1)
  unsigned short* Kb  = (unsigned short*)(ws + 35651584);      // 8 MB
  unsigned short* Vt  = (unsigned short*)(ws + 44040192);      // 8 MB [b*1024+he][s]

  k_prep<<<dim3(5120), dim3(256), 0, stream>>>(x, wq, wk, wv, wagg, Xb, Wall, Wat);

  k_proj<<<dim3(8, 32, 3), dim3(256), 0, stream>>>(Wall, Xb, Qb, Kb, Vt);

  k_stats  <<<dim3(1024), dim3(256), 0, stream>>>(Qb, Kb, mp, lp);
  k_mcomb  <<<dim3(256),  dim3(256), 0, stream>>>(mp, lp, m2, rl);
  k_scale_v<<<dim3(2048), dim3(256), 0, stream>>>(Vt, rl);

  k_attn<<<dim3(512),  dim3(256), 0, stream>>>(Qb, Kb, Vt, m2, Hd);
  k_agg <<<dim3(16, 32), dim3(256), 0, stream>>>(Wat, Hd, outp);
}

// Round 20
// 234.700 us; speedup vs baseline: 1.0410x; 1.0410x over previous
//
#include <hip/hip_runtime.h>
#include <hip/hip_bf16.h>

// SelfAttention: B=2,S=2048,D=1024,H=16,E=64. Softmax over QUERY axis.
//   Qb = (x@wq)*C1, Kb = x@wk, Vt = (x@wv)^T          (m97-style staged GEMM)
//   stats: m_t = max_s d (FULL), l_t = sum_s 2^(d-m_t) (two-pass, s split over 4)
//   ms_t = m_t + log2(l_t); attn: Hd = 2^(d-ms) @ V    (1/l folded into exponent)
//   out = Hd[4096][2048] @ WaT[1024][2048]             (staged GEMM, K=2048)
// R20: k_attn reverted to R18 32q/wave (R19's 64q/wave: occupancy 29->17.5%,
//      69.8us, FETCH unchanged -> amortization null, TLP loss real). NEW:
//      1/l folded into exponent (ms = m + log2 l as the C-init) -> k_scale_v
//      kernel + rl buffer + 16MB Vt round-trip deleted.

typedef __attribute__((ext_vector_type(8))) short bf16x8;
typedef __attribute__((ext_vector_type(4))) float f32x4;

#define C1 0.18033688011112042f  // log2(e)/8

__device__ __forceinline__ unsigned short f2bf(float f){
  union { __hip_bfloat16 h; unsigned short u; } cv;
  cv.h = __float2bfloat16(f);
  return cv.u;
}
__device__ __forceinline__ unsigned int pk2(float a, float b){
  union { __hip_bfloat162 h; unsigned int u; } cv;
  cv.h = __float22bfloat162_rn(make_float2(a, b));
  return cv.u;
}
__device__ __forceinline__ unsigned long long pack4(float a, float b, float c, float d){
  return (unsigned long long)pk2(a, b) | ((unsigned long long)pk2(c, d) << 32);
}
__device__ __forceinline__ float bf2f(unsigned short u){
  unsigned int x = ((unsigned int)u) << 16;
  return __builtin_bit_cast(float, x);
}

// ---- lane-half / lane-16-group exchanges (gfx950 permlane*_swap, shfl fallback)
__device__ __forceinline__ void swap32(unsigned a, unsigned b, unsigned &x, unsigned &y){
#if __has_builtin(__builtin_amdgcn_permlane32_swap)
  auto r = __builtin_amdgcn_permlane32_swap(a, b, false, false);
  x = r[0]; y = r[1];
#else
  int lane = threadIdx.x & 63;
  unsigned as = __shfl_xor((int)a, 32), bs = __shfl_xor((int)b, 32);
  x = (lane & 32) ? bs : a;
  y = (lane & 32) ? b : as;
#endif
}
__device__ __forceinline__ void swap16(unsigned a, unsigned b, unsigned &x, unsigned &y){
#if __has_builtin(__builtin_amdgcn_permlane16_swap)
  auto r = __builtin_amdgcn_permlane16_swap(a, b, false, false);
  x = r[0]; y = r[1];
#else
  int lane = threadIdx.x & 63;
  unsigned as = __shfl_xor((int)a, 16), bs = __shfl_xor((int)b, 16);
  x = (lane & 16) ? bs : a;
  y = (lane & 16) ? b : as;
#endif
}

#define GLOAD16(SRC, DST)                                                        \
  __builtin_amdgcn_global_load_lds(                                              \
      (const __attribute__((address_space(1))) void*)(SRC),                      \
      (__attribute__((address_space(3))) void*)(DST), 16, 0, 0)

// ---------------- merged prep: x->bf16, w3 transpose, wagg transpose -----------
// flat grid 5120: [0,4096) cvt_x ; [4096,4864) w3t ; [4864,5120) waggt
__global__ __launch_bounds__(256) void k_prep(const float* __restrict__ x,
                                              const float* __restrict__ wq,
                                              const float* __restrict__ wk,
                                              const float* __restrict__ wv,
                                              const float* __restrict__ wagg,
                                              unsigned short* __restrict__ Xb,
                                              unsigned short* __restrict__ Wall,
                                              unsigned short* __restrict__ Wat){
  __shared__ unsigned short T[64][72];
  int bid = blockIdx.x;
  if (bid < 4096){
    int i = (bid * 256 + threadIdx.x) * 4;
    float4 v = *reinterpret_cast<const float4*>(x + i);
    *reinterpret_cast<unsigned long long*>(Xb + i) = pack4(v.x, v.y, v.z, v.w);
    return;
  }
  bid -= 4096;
  const int r = threadIdx.x >> 2, c0 = (threadIdx.x & 3) << 4;
  if (bid < 768){
    const int z = bid >> 8, rem = bid & 255, hy = rem >> 4, dt = rem & 15;
    const float* w = ((z == 0) ? wq : ((z == 1) ? wk : wv)) + ((size_t)hy << 16);
    const int d0 = dt * 64;
    const float* src = w + ((size_t)(d0 + r) << 6) + c0;
#pragma unroll
    for (int i = 0; i < 4; ++i){
      float4 v = *(const float4*)(src + 4 * i);
      T[r][c0 + 4 * i + 0] = f2bf(v.x);
      T[r][c0 + 4 * i + 1] = f2bf(v.y);
      T[r][c0 + 4 * i + 2] = f2bf(v.z);
      T[r][c0 + 4 * i + 3] = f2bf(v.w);
    }
    __syncthreads();
    const int e = threadIdx.x >> 2, k0 = (threadIdx.x & 3) << 4;
    union { unsigned short s[8]; bf16x8 v; } u0, u1;
#pragma unroll
    for (int k = 0; k < 8; ++k){ u0.s[k] = T[k0 + k][e]; u1.s[k] = T[k0 + 8 + k][e]; }
    unsigned short* dst = Wall + ((size_t)z << 20) + (((size_t)hy * 64 + e) << 10) + d0 + k0;
    *(bf16x8*)dst = u0.v;
    *(bf16x8*)(dst + 8) = u1.v;
    return;
  }
  bid -= 768;
  {
    const int het = bid >> 4, dt = bid & 15;
    const int d0 = dt * 64, he0 = het * 64;
    const float* src = wagg + ((size_t)(he0 + r) << 10) + d0 + c0;
#pragma unroll
    for (int i = 0; i < 4; ++i){
      float4 v = *(const float4*)(src + 4 * i);
      T[r][c0 + 4 * i + 0] = f2bf(v.x);
      T[r][c0 + 4 * i + 1] = f2bf(v.y);
      T[r][c0 + 4 * i + 2] = f2bf(v.z);
      T[r][c0 + 4 * i + 3] = f2bf(v.w);
    }
    __syncthreads();
    const int d = threadIdx.x >> 2, k0 = (threadIdx.x & 3) << 4;
    union { unsigned short s[8]; bf16x8 v; } u0, u1;
#pragma unroll
    for (int k = 0; k < 8; ++k){ u0.s[k] = T[k0 + k][d]; u1.s[k] = T[k0 + 8 + k][d]; }
    unsigned short* dst = Wat + ((size_t)(d0 + d) << 11) + he0 + k0;
    *(bf16x8*)dst = u0.v;
    *(bf16x8*)(dst + 8) = u1.v;
    *(bf16x8*)(dst + 1024) = u0.v;
    *(bf16x8*)(dst + 1032) = u1.v;
  }
}

// ---------------- staged GEMM: projections ----------------
__global__ __launch_bounds__(256) void k_proj(const unsigned short* __restrict__ Wall,
                                              const unsigned short* __restrict__ Xb,
                                              unsigned short* __restrict__ Qb,
                                              unsigned short* __restrict__ Kb,
                                              unsigned short* __restrict__ Vt){
  __shared__ __align__(16) unsigned short lds[2][2][4096];
  const int z = blockIdx.z;
  const unsigned short* Wt = Wall + ((size_t)z << 20);
  const int t = threadIdx.x;
  const int w = t >> 6, lane = t & 63, g = lane >> 4, cl = lane & 15;
  const int wn = w >> 1, wm = w & 1;
  const int n0 = blockIdx.x * 128, m0 = blockIdx.y * 128;

  const int rowS = t & 127;
  const unsigned short* sA = Wt + (size_t)(n0 + rowS) * 1024 + (t >> 7) * 8;
  const unsigned short* sB = Xb + (size_t)(m0 + rowS) * 1024 + (t >> 7) * 8;

  f32x4 acc[4][4];
#pragma unroll
  for (int i = 0; i < 4; ++i)
#pragma unroll
    for (int j = 0; j < 4; ++j) acc[i][j] = f32x4{0.f, 0.f, 0.f, 0.f};

  GLOAD16(sA,      &lds[0][0][t * 8]);
  GLOAD16(sA + 16, &lds[0][0][t * 8 + 2048]);
  GLOAD16(sB,      &lds[0][1][t * 8]);
  GLOAD16(sB + 16, &lds[0][1][t * 8 + 2048]);
  __syncthreads();

#pragma unroll 2
  for (int kt = 0; kt < 32; ++kt){
    const int cur = kt & 1;
    if (kt < 31){
      const unsigned short* nA = sA + (kt + 1) * 32;
      const unsigned short* nB = sB + (kt + 1) * 32;
      GLOAD16(nA,      &lds[cur ^ 1][0][t * 8]);
      GLOAD16(nA + 16, &lds[cur ^ 1][0][t * 8 + 2048]);
      GLOAD16(nB,      &lds[cur ^ 1][1][t * 8]);
      GLOAD16(nB + 16, &lds[cur ^ 1][1][t * 8 + 2048]);
    }
    const unsigned short* la = &lds[cur][0][g * 1024];
    const unsigned short* lb = &lds[cur][1][g * 1024];
    bf16x8 af[4], bq[4];
#pragma unroll
    for (int i = 0; i < 4; ++i) af[i] = *(const bf16x8*)(la + (wn * 64 + i * 16 + cl) * 8);
#pragma unroll
    for (int j = 0; j < 4; ++j) bq[j] = *(const bf16x8*)(lb + (wm * 64 + j * 16 + cl) * 8);
#pragma unroll
    for (int i = 0; i < 4; ++i)
#pragma unroll
      for (int j = 0; j < 4; ++j)
        acc[i][j] = __builtin_amdgcn_mfma_f32_16x16x32_bf16(af[i], bq[j], acc[i][j], 0, 0, 0);
    __syncthreads();
  }

  const float scale = (z == 0) ? C1 : 1.f;
#pragma unroll
  for (int i = 0; i < 4; ++i)
#pragma unroll
    for (int j = 0; j < 4; ++j)
#pragma unroll
      for (int jj = 0; jj < 4; ++jj) acc[i][j][jj] *= scale;

  if (z < 2){
    unsigned short* outp = (z == 0) ? Qb : Kb;
#pragma unroll
    for (int i = 0; i < 4; ++i)
#pragma unroll
      for (int j = 0; j < 4; ++j){
        int m = m0 + wm * 64 + 16 * j + cl;
        int n = n0 + wn * 64 + 16 * i + 4 * g;
        *reinterpret_cast<unsigned long long*>(outp + (size_t)m * 1024 + n) =
            pack4(acc[i][j][0], acc[i][j][1], acc[i][j][2], acc[i][j][3]);
      }
  } else {
    int b = m0 >> 11;
#pragma unroll
    for (int i = 0; i < 4; ++i)
#pragma unroll
      for (int j = 0; j < 4; ++j){
        int c2 = (m0 & 2047) + wm * 64 + 16 * j + cl;
        int nb = b * 1024 + n0 + wn * 64 + 16 * i + 4 * g;
#pragma unroll
        for (int jj = 0; jj < 4; ++jj)
          Vt[(size_t)(nb + jj) * 2048 + c2] = f2bf(acc[i][j][jj]);
      }
  }
}

// ---------------- staged GEMM: output projection (128m x 64n, 512 blocks) ------
__global__ __launch_bounds__(256) void k_agg(const unsigned short* __restrict__ Wa,
                                             const unsigned short* __restrict__ Hd,
                                             float* __restrict__ outp){
  __shared__ __align__(16) unsigned short lds[2][6144];  // A[4][64][8] | B[4][128][8]
  const int t = threadIdx.x;
  const int w = t >> 6, lane = t & 63, g = lane >> 4, cl = lane & 15;
  const int wn = w >> 1, wm = w & 1;
  const int n0 = blockIdx.x * 64, m0 = blockIdx.y * 128;

  const unsigned short* sA  = Wa + (size_t)(n0 + (t & 63)) * 2048 + (t >> 6) * 8;
  const unsigned short* sB1 = Hd + (size_t)(m0 + (t & 127)) * 2048 + (t >> 7) * 8;
  unsigned short* dA0  = &lds[0][0]    + t * 8;
  unsigned short* dB10 = &lds[0][2048] + t * 8;

  f32x4 acc[2][4];
#pragma unroll
  for (int j = 0; j < 2; ++j)
#pragma unroll
    for (int i = 0; i < 4; ++i) acc[j][i] = f32x4{0.f, 0.f, 0.f, 0.f};

  GLOAD16(sA,       dA0);
  GLOAD16(sB1,      dB10);
  GLOAD16(sB1 + 16, dB10 + 2048);
  __syncthreads();

#pragma unroll 2
  for (int kt = 0; kt < 64; ++kt){
    const int cur = kt & 1;
    if (kt < 63){
      const unsigned short* nA = sA  + (kt + 1) * 32;
      const unsigned short* nB = sB1 + (kt + 1) * 32;
      GLOAD16(nA,      dA0  + (cur ^ 1) * 6144);
      GLOAD16(nB,      dB10 + (cur ^ 1) * 6144);
      GLOAD16(nB + 16, dB10 + (cur ^ 1) * 6144 + 2048);
    }
    const unsigned short* la = &lds[cur][0];
    const unsigned short* lb = &lds[cur][2048];
    bf16x8 af[2], bq[4];
#pragma unroll
    for (int j = 0; j < 2; ++j) af[j] = *(const bf16x8*)(la + g * 512 + (wn * 32 + j * 16 + cl) * 8);
#pragma unroll
    for (int i = 0; i < 4; ++i) bq[i] = *(const bf16x8*)(lb + g * 1024 + (wm * 64 + i * 16 + cl) * 8);
#pragma unroll
    for (int j = 0; j < 2; ++j)
#pragma unroll
      for (int i = 0; i < 4; ++i)
        acc[j][i] = __builtin_amdgcn_mfma_f32_16x16x32_bf16(af[j], bq[i], acc[j][i], 0, 0, 0);
    __syncthreads();
  }
#pragma unroll
  for (int j = 0; j < 2; ++j)
#pragma unroll
    for (int i = 0; i < 4; ++i){
      int m = m0 + wm * 64 + 16 * i + cl;
      int n = n0 + wn * 32 + 16 * j + 4 * g;
      *reinterpret_cast<f32x4*>(outp + (size_t)m * 1024 + n) = acc[j][i];
    }
}

// ---------------- stats: LDS-staged Q, two-pass FULL max, s split over 4 --------
__global__ __launch_bounds__(256, 4) void k_stats(const unsigned short* __restrict__ Qb,
                                                  const unsigned short* __restrict__ Kb,
                                                  float* __restrict__ mp,
                                                  float* __restrict__ lp){
  __shared__ __align__(16) unsigned short Qs[2][64][64];
  const int B = blockIdx.x;
  const int xcd = B & 7, rest = B >> 3;
  const int tx = rest & 7, gi = rest >> 3;
  const int grp = xcd + 8 * gi;
  const int bh = grp & 31, z = grp >> 5;
  const int b = bh >> 4, h = bh & 15;
  const int w = threadIdx.x >> 6, lane = threadIdx.x & 63;
  const int g = lane >> 4, cl = lane & 15;
  const int t0 = tx * 256 + w * 64;

  const unsigned short* kp = Kb + (size_t)(b * 2048 + t0 + cl) * 1024 + h * 64 + g * 8;
  bf16x8 a[4][2];
#pragma unroll
  for (int ti = 0; ti < 4; ++ti){
    a[ti][0] = *(const bf16x8*)(kp + (size_t)ti * 16 * 1024);
    a[ti][1] = *(const bf16x8*)(kp + (size_t)ti * 16 * 1024 + 32);
  }

  const int r0 = threadIdx.x >> 3, sl = threadIdx.x & 7;
  const unsigned short* qsrc = Qb + (size_t)(b * 2048 + z * 512 + r0) * 1024 + h * 64
                               + ((sl ^ (r0 & 7)) * 8);
  unsigned short* qdst0 = &Qs[0][0][0] + threadIdx.x * 8;

  const int e0 = (g ^ (cl & 7)) * 8;
  const int e1 = ((g + 4) ^ (cl & 7)) * 8;

  float m[16], l[16];
#pragma unroll
  for (int i = 0; i < 16; ++i){ m[i] = -3.0e38f; l[i] = 0.f; }

  // ---- pass 1: max ----
  GLOAD16(qsrc,             qdst0);
  GLOAD16(qsrc + 32 * 1024, qdst0 + 2048);
  __syncthreads();
  for (int c = 0; c < 8; ++c){
    const int buf = c & 1;
    if (c < 7){
      const unsigned short* s2 = qsrc + (size_t)(c + 1) * 64 * 1024;
      unsigned short* d2 = qdst0 + (buf ^ 1) * 4096;
      GLOAD16(s2,             d2);
      GLOAD16(s2 + 32 * 1024, d2 + 2048);
    }
#pragma unroll
    for (int st = 0; st < 4; ++st){
      const unsigned short* qrow = &Qs[buf][st * 16 + cl][0];
      bf16x8 b0 = *(const bf16x8*)(qrow + e0);
      bf16x8 b1 = *(const bf16x8*)(qrow + e1);
#pragma unroll
      for (int ti = 0; ti < 4; ++ti){
        f32x4 zz = {0.f, 0.f, 0.f, 0.f};
        f32x4 d = __builtin_amdgcn_mfma_f32_16x16x32_bf16(a[ti][0], b0, zz, 0, 0, 0);
        d = __builtin_amdgcn_mfma_f32_16x16x32_bf16(a[ti][1], b1, d, 0, 0, 0);
#pragma unroll
        for (int j = 0; j < 4; ++j) m[ti * 4 + j] = fmaxf(m[ti * 4 + j], d[j]);
      }
    }
    __syncthreads();
  }
#pragma unroll
  for (int off = 1; off < 16; off <<= 1)
#pragma unroll
    for (int i = 0; i < 16; ++i) m[i] = fmaxf(m[i], __shfl_xor(m[i], off));

  // ---- pass 2: sum of 2^(d-m) (zero-C, explicit subtract) ----
  GLOAD16(qsrc,             qdst0);
  GLOAD16(qsrc + 32 * 1024, qdst0 + 2048);
  __syncthreads();
  for (int c = 0; c < 8; ++c){
    const int buf = c & 1;
    if (c < 7){
      const unsigned short* s2 = qsrc + (size_t)(c + 1) * 64 * 1024;
      unsigned short* d2 = qdst0 + (buf ^ 1) * 4096;
      GLOAD16(s2,             d2);
      GLOAD16(s2 + 32 * 1024, d2 + 2048);
    }
#pragma unroll
    for (int st = 0; st < 4; ++st){
      const unsigned short* qrow = &Qs[buf][st * 16 + cl][0];
      bf16x8 b0 = *(const bf16x8*)(qrow + e0);
      bf16x8 b1 = *(const bf16x8*)(qrow + e1);
#pragma unroll
      for (int ti = 0; ti < 4; ++ti){
        f32x4 zz = {0.f, 0.f, 0.f, 0.f};
        f32x4 d = __builtin_amdgcn_mfma_f32_16x16x32_bf16(a[ti][0], b0, zz, 0, 0, 0);
        d = __builtin_amdgcn_mfma_f32_16x16x32_bf16(a[ti][1], b1, d, 0, 0, 0);
#pragma unroll
        for (int j = 0; j < 4; ++j) l[ti * 4 + j] += exp2f(d[j] - m[ti * 4 + j]);
      }
    }
    __syncthreads();
  }
#pragma unroll
  for (int off = 1; off < 16; off <<= 1)
#pragma unroll
    for (int i = 0; i < 16; ++i) l[i] += __shfl_xor(l[i], off);

  if (cl == 0){
    size_t base = ((size_t)z * 32 + bh) * 2048 + t0;
#pragma unroll
    for (int ti = 0; ti < 4; ++ti){
      f32x4 mv = {m[ti * 4 + 0], m[ti * 4 + 1], m[ti * 4 + 2], m[ti * 4 + 3]};
      f32x4 lv = {l[ti * 4 + 0], l[ti * 4 + 1], l[ti * 4 + 2], l[ti * 4 + 3]};
      *(f32x4*)(mp + base + ti * 16 + 4 * g) = mv;
      *(f32x4*)(lp + base + ti * 16 + 4 * g) = lv;
    }
  }
}

// combine the four s-quarter partials -> ms = m + log2(l)  (the softmax "logit
// normalizer"; 1/l is applied inside k_attn's exponent via C-init = -ms)
__global__ void k_mcomb(const float* __restrict__ mp, const float* __restrict__ lp,
                        float* __restrict__ ms){
  int i = blockIdx.x * 256 + threadIdx.x;   // 65536
  float m0 = mp[i], m1 = mp[65536 + i], m2v = mp[131072 + i], m3 = mp[196608 + i];
  float l0 = lp[i], l1 = lp[65536 + i], l2 = lp[131072 + i], l3 = lp[196608 + i];
  float m = fmaxf(fmaxf(m0, m1), fmaxf(m2v, m3));
  float l = l0 * exp2f(m0 - m) + l1 * exp2f(m1 - m)
          + l2 * exp2f(m2v - m) + l3 * exp2f(m3 - m);
  ms[i] = m + log2f(l);
}

// ---------------- attention: 64-key chunks, P in registers, -ms in LDS as C ----
// grid 1024 flat (3|4|3 bits = xcd|sx|gi): 16 sx x (32 bh x 2 z).
__global__ __launch_bounds__(256, 4) void k_attn(const unsigned short* __restrict__ Qb,
                                                 const unsigned short* __restrict__ Kb,
                                                 const unsigned short* __restrict__ Vt,
                                                 const float* __restrict__ ms,
                                                 unsigned short* __restrict__ Hd){
  __shared__ __align__(16) unsigned short KsL[2 * 64 * 64];  // 16 KB: [key][e]
  __shared__ __align__(16) unsigned short VsL[2 * 64 * 64];  // 16 KB: [e][t-chunk]
  __shared__ __align__(16) float Ms[1024];                   //  4 KB: NEGATED ms
  const int B = blockIdx.x;
  const int xcd = B & 7, rest = B >> 3;
  const int sx = rest & 15, gi = rest >> 4;         // gi 0..7
  const int grp = xcd + 8 * gi;                     // 0..63 = bh + 32*z
  const int bh = grp & 31, z = grp >> 5;            // z 0..1
  const int b = bh >> 4, h = bh & 15;
  const int lane = threadIdx.x & 63;
  const int g = lane >> 4, cl = lane & 15;
  const int s0w = sx * 128 + (threadIdx.x >> 6) * 32;
  const int tbase = z * 1024;

  // stage NEGATED ms slice for this (bh, z): used directly as MFMA C-init
  {
    int i = threadIdx.x * 4;
    f32x4 mv = *(const f32x4*)(ms + (size_t)bh * 2048 + tbase + i);
    *(f32x4*)&Ms[i] = f32x4{-mv[0], -mv[1], -mv[2], -mv[3]};
  }

  bf16x8 q[2][2];
#pragma unroll
  for (int ss = 0; ss < 2; ++ss){
    const unsigned short* qp = Qb + (size_t)(b * 2048 + s0w + ss * 16 + cl) * 1024 + h * 64 + g * 8;
    q[ss][0] = *(const bf16x8*)(qp);
    q[ss][1] = *(const bf16x8*)(qp + 32);
  }
  f32x4 acc[4][2];
#pragma unroll
  for (int i = 0; i < 4; ++i)
#pragma unroll
    for (int ss = 0; ss < 2; ++ss) acc[i][ss] = f32x4{0.f, 0.f, 0.f, 0.f};

  const int srow = threadIdx.x >> 3;
  const int sseg = ((threadIdx.x & 7) ^ (srow & 7)) * 8;
  const unsigned short* kStage = Kb + (size_t)(b * 2048 + tbase + srow) * 1024 + h * 64 + sseg;
  const unsigned short* vStage = Vt + (size_t)(b * 1024 + h * 64 + srow) * 2048 + tbase + sseg;
  unsigned short* kDst = &KsL[0] + threadIdx.x * 8;
  unsigned short* vDst = &VsL[0] + threadIdx.x * 8;

  const int eK = (g ^ (cl & 7)) * 8;
  const int eK2 = ((g + 4) ^ (cl & 7)) * 8;

#define ASTAGE(c, buf) {                                                          \
    const unsigned short* ks_ = kStage + (size_t)(c) * 64 * 1024;                 \
    const unsigned short* vs_ = vStage + (c) * 64;                                \
    unsigned short* kd_ = kDst + (buf) * 4096;                                    \
    unsigned short* vd_ = vDst + (buf) * 4096;                                    \
    GLOAD16(ks_,             kd_);                                                \
    GLOAD16(ks_ + 32 * 1024, kd_ + 2048);                                         \
    GLOAD16(vs_,             vd_);                                                \
    GLOAD16(vs_ + (size_t)32 * 2048, vd_ + 2048); }

  ASTAGE(0, 0);
  __syncthreads();

  for (int c = 0; c < 16; ++c){
    const int buf = c & 1;
    if (c < 15) ASTAGE(c + 1, buf ^ 1);
    const unsigned short* Kbuf = &KsL[0] + buf * 4096;
    const unsigned short* Vbuf = &VsL[0] + buf * 4096;
#pragma unroll
    for (int sc = 0; sc < 2; ++sc){
      const unsigned short* kr0 = Kbuf + (sc * 32 + cl) * 64;
      const unsigned short* kr1 = Kbuf + (sc * 32 + 16 + cl) * 64;
      bf16x8 a00 = *(const bf16x8*)(kr0 + eK);
      bf16x8 a01 = *(const bf16x8*)(kr0 + eK2);
      bf16x8 a10 = *(const bf16x8*)(kr1 + eK);
      bf16x8 a11 = *(const bf16x8*)(kr1 + eK2);
      f32x4 ci0 = *(const f32x4*)&Ms[c * 64 + sc * 32 + 4 * g];        // = -ms
      f32x4 ci1 = *(const f32x4*)&Ms[c * 64 + sc * 32 + 16 + 4 * g];   // = -ms

      bf16x8 pb[2];
#pragma unroll
      for (int ss = 0; ss < 2; ++ss){
        __builtin_amdgcn_s_setprio(1);
        f32x4 d0 = __builtin_amdgcn_mfma_f32_16x16x32_bf16(a00, q[ss][0], ci0, 0, 0, 0);
        d0 = __builtin_amdgcn_mfma_f32_16x16x32_bf16(a01, q[ss][1], d0, 0, 0, 0);
        f32x4 d1 = __builtin_amdgcn_mfma_f32_16x16x32_bf16(a10, q[ss][0], ci1, 0, 0, 0);
        d1 = __builtin_amdgcn_mfma_f32_16x16x32_bf16(a11, q[ss][1], d1, 0, 0, 0);
        __builtin_amdgcn_s_setprio(0);
        unsigned w00 = pk2(exp2f(d0[0]), exp2f(d0[1]));
        unsigned w01 = pk2(exp2f(d0[2]), exp2f(d0[3]));
        unsigned w10 = pk2(exp2f(d1[0]), exp2f(d1[1]));
        unsigned w11 = pk2(exp2f(d1[2]), exp2f(d1[3]));
        unsigned sa0, sb0, sa1, sb1, W0, W1, W2, W3;
        swap32(w00, w10, sa0, sb0);
        swap32(w01, w11, sa1, sb1);
        swap16(sa0, sb0, W0, W2);
        swap16(sa1, sb1, W1, W3);
        union { unsigned u[4]; bf16x8 v; } fr;
        fr.u[0] = W0; fr.u[1] = W1; fr.u[2] = W2; fr.u[3] = W3;
        pb[ss] = fr.v;
      }
      __builtin_amdgcn_s_setprio(1);
#pragma unroll
      for (int i = 0; i < 4; ++i){
        bf16x8 av = *(const bf16x8*)(Vbuf + (16 * i + cl) * 64 + ((sc * 4 + g) ^ (cl & 7)) * 8);
        acc[i][0] = __builtin_amdgcn_mfma_f32_16x16x32_bf16(av, pb[0], acc[i][0], 0, 0, 0);
        acc[i][1] = __builtin_amdgcn_mfma_f32_16x16x32_bf16(av, pb[1], acc[i][1], 0, 0, 0);
      }
      __builtin_amdgcn_s_setprio(0);
    }
    __syncthreads();
  }
#undef ASTAGE
#pragma unroll
  for (int i = 0; i < 4; ++i)
#pragma unroll
    for (int ss = 0; ss < 2; ++ss){
      *reinterpret_cast<unsigned long long*>(
          Hd + (size_t)(b * 2048 + s0w + ss * 16 + cl) * 2048 + z * 1024 + h * 64 + 16 * i + 4 * g) =
          pack4(acc[i][ss][0], acc[i][ss][1], acc[i][ss][2], acc[i][ss][3]);
    }
}

extern "C" void kernel_launch(void* const* d_in, const int* in_sizes, int n_in,
                              void* d_out, int out_size, void* d_ws, size_t ws_size,
                              hipStream_t stream) {
  const float* x    = (const float*)d_in[0];
  const float* wq   = (const float*)d_in[2];
  const float* wk   = (const float*)d_in[3];
  const float* wv   = (const float*)d_in[4];
  const float* wagg = (const float*)d_in[5];
  float* outp = (float*)d_out;

  char* ws = (char*)d_ws;
  unsigned short* Xb  = (unsigned short*)(ws);                 // 8MB, dead after k_proj
  unsigned short* Hd  = (unsigned short*)(ws);                 // 16MB [4096][2048]
  unsigned short* Wall= (unsigned short*)(ws + 16777216);      // 6MB, dead after k_proj
  float* mp = (float*)(ws + 16777216);                         // 1 MB [4][32][2048]
  float* lp = (float*)(ws + 17825792);                         // 1 MB
  float* msb= (float*)(ws + 18874368);                         // 256 KB (ms = m+log2 l)
  unsigned short* Wat = (unsigned short*)(ws + 23068672);      // 4 MB [d][2048]
  unsigned short* Qb  = (unsigned short*)(ws + 27262976);      // 8 MB (pre-scaled by C1)
  unsigned short* Kb  = (unsigned short*)(ws + 35651584);      // 8 MB
  unsigned short* Vt  = (unsigned short*)(ws + 44040192);      // 8 MB [b*1024+he][s]

  k_prep<<<dim3(5120), dim3(256), 0, stream>>>(x, wq, wk, wv, wagg, Xb, Wall, Wat);

  k_proj<<<dim3(8, 32, 3), dim3(256), 0, stream>>>(Wall, Xb, Qb, Kb, Vt);

  k_stats<<<dim3(1024), dim3(256), 0, stream>>>(Qb, Kb, mp, lp);
  k_mcomb<<<dim3(256),  dim3(256), 0, stream>>>(mp, lp, msb);

  k_attn<<<dim3(1024), dim3(256), 0, stream>>>(Qb, Kb, Vt, msb, Hd);
  k_agg <<<dim3(16, 32), dim3(256), 0, stream>>>(Wat, Hd, outp);
}

// Round 21
// 233.857 us; speedup vs baseline: 1.0448x; 1.0036x over previous
//
#include <hip/hip_runtime.h>
#include <hip/hip_bf16.h>

// SelfAttention: B=2,S=2048,D=1024,H=16,E=64. Softmax over QUERY axis.
//   Qb = (x@wq)*C1, Kb = x@wk, Vt = (x@wv)^T          (m97-style staged GEMM)
//   stats: m_t = max_s d (FULL), l_t = sum_s 2^(d-m_t) (two-pass, s split over 4)
//   attn: Hd = 2^(d-ms) @ V with ms = m + log2(l) combined INLINE in prologue
//   out = Hd[4096][2048] @ WaT[1024][2048]             (staged GEMM, K=2048)
// R21: k_mcomb fused into k_attn prologue (each block combines its 1024-slice
//      from mp/lp with the identical fmax/exp2/log2 tree; 128B/thread coalesced;
//      combine duplicated 16x across s-blocks ~ +1us L2, -1 dispatch). 5 kernels.
//      All else frozen at R20 (measured best 234.7us).

typedef __attribute__((ext_vector_type(8))) short bf16x8;
typedef __attribute__((ext_vector_type(4))) float f32x4;

#define C1 0.18033688011112042f  // log2(e)/8

__device__ __forceinline__ unsigned short f2bf(float f){
  union { __hip_bfloat16 h; unsigned short u; } cv;
  cv.h = __float2bfloat16(f);
  return cv.u;
}
__device__ __forceinline__ unsigned int pk2(float a, float b){
  union { __hip_bfloat162 h; unsigned int u; } cv;
  cv.h = __float22bfloat162_rn(make_float2(a, b));
  return cv.u;
}
__device__ __forceinline__ unsigned long long pack4(float a, float b, float c, float d){
  return (unsigned long long)pk2(a, b) | ((unsigned long long)pk2(c, d) << 32);
}
__device__ __forceinline__ float bf2f(unsigned short u){
  unsigned int x = ((unsigned int)u) << 16;
  return __builtin_bit_cast(float, x);
}

// ---- lane-half / lane-16-group exchanges (gfx950 permlane*_swap, shfl fallback)
__device__ __forceinline__ void swap32(unsigned a, unsigned b, unsigned &x, unsigned &y){
#if __has_builtin(__builtin_amdgcn_permlane32_swap)
  auto r = __builtin_amdgcn_permlane32_swap(a, b, false, false);
  x = r[0]; y = r[1];
#else
  int lane = threadIdx.x & 63;
  unsigned as = __shfl_xor((int)a, 32), bs = __shfl_xor((int)b, 32);
  x = (lane & 32) ? bs : a;
  y = (lane & 32) ? b : as;
#endif
}
__device__ __forceinline__ void swap16(unsigned a, unsigned b, unsigned &x, unsigned &y){
#if __has_builtin(__builtin_amdgcn_permlane16_swap)
  auto r = __builtin_amdgcn_permlane16_swap(a, b, false, false);
  x = r[0]; y = r[1];
#else
  int lane = threadIdx.x & 63;
  unsigned as = __shfl_xor((int)a, 16), bs = __shfl_xor((int)b, 16);
  x = (lane & 16) ? bs : a;
  y = (lane & 16) ? b : as;
#endif
}

#define GLOAD16(SRC, DST)                                                        \
  __builtin_amdgcn_global_load_lds(                                              \
      (const __attribute__((address_space(1))) void*)(SRC),                      \
      (__attribute__((address_space(3))) void*)(DST), 16, 0, 0)

// ---------------- merged prep: x->bf16, w3 transpose, wagg transpose -----------
// flat grid 5120: [0,4096) cvt_x ; [4096,4864) w3t ; [4864,5120) waggt
__global__ __launch_bounds__(256) void k_prep(const float* __restrict__ x,
                                              const float* __restrict__ wq,
                                              const float* __restrict__ wk,
                                              const float* __restrict__ wv,
                                              const float* __restrict__ wagg,
                                              unsigned short* __restrict__ Xb,
                                              unsigned short* __restrict__ Wall,
                                              unsigned short* __restrict__ Wat){
  __shared__ unsigned short T[64][72];
  int bid = blockIdx.x;
  if (bid < 4096){
    int i = (bid * 256 + threadIdx.x) * 4;
    float4 v = *reinterpret_cast<const float4*>(x + i);
    *reinterpret_cast<unsigned long long*>(Xb + i) = pack4(v.x, v.y, v.z, v.w);
    return;
  }
  bid -= 4096;
  const int r = threadIdx.x >> 2, c0 = (threadIdx.x & 3) << 4;
  if (bid < 768){
    const int z = bid >> 8, rem = bid & 255, hy = rem >> 4, dt = rem & 15;
    const float* w = ((z == 0) ? wq : ((z == 1) ? wk : wv)) + ((size_t)hy << 16);
    const int d0 = dt * 64;
    const float* src = w + ((size_t)(d0 + r) << 6) + c0;
#pragma unroll
    for (int i = 0; i < 4; ++i){
      float4 v = *(const float4*)(src + 4 * i);
      T[r][c0 + 4 * i + 0] = f2bf(v.x);
      T[r][c0 + 4 * i + 1] = f2bf(v.y);
      T[r][c0 + 4 * i + 2] = f2bf(v.z);
      T[r][c0 + 4 * i + 3] = f2bf(v.w);
    }
    __syncthreads();
    const int e = threadIdx.x >> 2, k0 = (threadIdx.x & 3) << 4;
    union { unsigned short s[8]; bf16x8 v; } u0, u1;
#pragma unroll
    for (int k = 0; k < 8; ++k){ u0.s[k] = T[k0 + k][e]; u1.s[k] = T[k0 + 8 + k][e]; }
    unsigned short* dst = Wall + ((size_t)z << 20) + (((size_t)hy * 64 + e) << 10) + d0 + k0;
    *(bf16x8*)dst = u0.v;
    *(bf16x8*)(dst + 8) = u1.v;
    return;
  }
  bid -= 768;
  {
    const int het = bid >> 4, dt = bid & 15;
    const int d0 = dt * 64, he0 = het * 64;
    const float* src = wagg + ((size_t)(he0 + r) << 10) + d0 + c0;
#pragma unroll
    for (int i = 0; i < 4; ++i){
      float4 v = *(const float4*)(src + 4 * i);
      T[r][c0 + 4 * i + 0] = f2bf(v.x);
      T[r][c0 + 4 * i + 1] = f2bf(v.y);
      T[r][c0 + 4 * i + 2] = f2bf(v.z);
      T[r][c0 + 4 * i + 3] = f2bf(v.w);
    }
    __syncthreads();
    const int d = threadIdx.x >> 2, k0 = (threadIdx.x & 3) << 4;
    union { unsigned short s[8]; bf16x8 v; } u0, u1;
#pragma unroll
    for (int k = 0; k < 8; ++k){ u0.s[k] = T[k0 + k][d]; u1.s[k] = T[k0 + 8 + k][d]; }
    unsigned short* dst = Wat + ((size_t)(d0 + d) << 11) + he0 + k0;
    *(bf16x8*)dst = u0.v;
    *(bf16x8*)(dst + 8) = u1.v;
    *(bf16x8*)(dst + 1024) = u0.v;
    *(bf16x8*)(dst + 1032) = u1.v;
  }
}

// ---------------- staged GEMM: projections ----------------
__global__ __launch_bounds__(256) void k_proj(const unsigned short* __restrict__ Wall,
                                              const unsigned short* __restrict__ Xb,
                                              unsigned short* __restrict__ Qb,
                                              unsigned short* __restrict__ Kb,
                                              unsigned short* __restrict__ Vt){
  __shared__ __align__(16) unsigned short lds[2][2][4096];
  const int z = blockIdx.z;
  const unsigned short* Wt = Wall + ((size_t)z << 20);
  const int t = threadIdx.x;
  const int w = t >> 6, lane = t & 63, g = lane >> 4, cl = lane & 15;
  const int wn = w >> 1, wm = w & 1;
  const int n0 = blockIdx.x * 128, m0 = blockIdx.y * 128;

  const int rowS = t & 127;
  const unsigned short* sA = Wt + (size_t)(n0 + rowS) * 1024 + (t >> 7) * 8;
  const unsigned short* sB = Xb + (size_t)(m0 + rowS) * 1024 + (t >> 7) * 8;

  f32x4 acc[4][4];
#pragma unroll
  for (int i = 0; i < 4; ++i)
#pragma unroll
    for (int j = 0; j < 4; ++j) acc[i][j] = f32x4{0.f, 0.f, 0.f, 0.f};

  GLOAD16(sA,      &lds[0][0][t * 8]);
  GLOAD16(sA + 16, &lds[0][0][t * 8 + 2048]);
  GLOAD16(sB,      &lds[0][1][t * 8]);
  GLOAD16(sB + 16, &lds[0][1][t * 8 + 2048]);
  __syncthreads();

#pragma unroll 2
  for (int kt = 0; kt < 32; ++kt){
    const int cur = kt & 1;
    if (kt < 31){
      const unsigned short* nA = sA + (kt + 1) * 32;
      const unsigned short* nB = sB + (kt + 1) * 32;
      GLOAD16(nA,      &lds[cur ^ 1][0][t * 8]);
      GLOAD16(nA + 16, &lds[cur ^ 1][0][t * 8 + 2048]);
      GLOAD16(nB,      &lds[cur ^ 1][1][t * 8]);
      GLOAD16(nB + 16, &lds[cur ^ 1][1][t * 8 + 2048]);
    }
    const unsigned short* la = &lds[cur][0][g * 1024];
    const unsigned short* lb = &lds[cur][1][g * 1024];
    bf16x8 af[4], bq[4];
#pragma unroll
    for (int i = 0; i < 4; ++i) af[i] = *(const bf16x8*)(la + (wn * 64 + i * 16 + cl) * 8);
#pragma unroll
    for (int j = 0; j < 4; ++j) bq[j] = *(const bf16x8*)(lb + (wm * 64 + j * 16 + cl) * 8);
#pragma unroll
    for (int i = 0; i < 4; ++i)
#pragma unroll
      for (int j = 0; j < 4; ++j)
        acc[i][j] = __builtin_amdgcn_mfma_f32_16x16x32_bf16(af[i], bq[j], acc[i][j], 0, 0, 0);
    __syncthreads();
  }

  const float scale = (z == 0) ? C1 : 1.f;
#pragma unroll
  for (int i = 0; i < 4; ++i)
#pragma unroll
    for (int j = 0; j < 4; ++j)
#pragma unroll
      for (int jj = 0; jj < 4; ++jj) acc[i][j][jj] *= scale;

  if (z < 2){
    unsigned short* outp = (z == 0) ? Qb : Kb;
#pragma unroll
    for (int i = 0; i < 4; ++i)
#pragma unroll
      for (int j = 0; j < 4; ++j){
        int m = m0 + wm * 64 + 16 * j + cl;
        int n = n0 + wn * 64 + 16 * i + 4 * g;
        *reinterpret_cast<unsigned long long*>(outp + (size_t)m * 1024 + n) =
            pack4(acc[i][j][0], acc[i][j][1], acc[i][j][2], acc[i][j][3]);
      }
  } else {
    int b = m0 >> 11;
#pragma unroll
    for (int i = 0; i < 4; ++i)
#pragma unroll
      for (int j = 0; j < 4; ++j){
        int c2 = (m0 & 2047) + wm * 64 + 16 * j + cl;
        int nb = b * 1024 + n0 + wn * 64 + 16 * i + 4 * g;
#pragma unroll
        for (int jj = 0; jj < 4; ++jj)
          Vt[(size_t)(nb + jj) * 2048 + c2] = f2bf(acc[i][j][jj]);
      }
  }
}

// ---------------- staged GEMM: output projection (128m x 64n, 512 blocks) ------
__global__ __launch_bounds__(256) void k_agg(const unsigned short* __restrict__ Wa,
                                             const unsigned short* __restrict__ Hd,
                                             float* __restrict__ outp){
  __shared__ __align__(16) unsigned short lds[2][6144];  // A[4][64][8] | B[4][128][8]
  const int t = threadIdx.x;
  const int w = t >> 6, lane = t & 63, g = lane >> 4, cl = lane & 15;
  const int wn = w >> 1, wm = w & 1;
  const int n0 = blockIdx.x * 64, m0 = blockIdx.y * 128;

  const unsigned short* sA  = Wa + (size_t)(n0 + (t & 63)) * 2048 + (t >> 6) * 8;
  const unsigned short* sB1 = Hd + (size_t)(m0 + (t & 127)) * 2048 + (t >> 7) * 8;
  unsigned short* dA0  = &lds[0][0]    + t * 8;
  unsigned short* dB10 = &lds[0][2048] + t * 8;

  f32x4 acc[2][4];
#pragma unroll
  for (int j = 0; j < 2; ++j)
#pragma unroll
    for (int i = 0; i < 4; ++i) acc[j][i] = f32x4{0.f, 0.f, 0.f, 0.f};

  GLOAD16(sA,       dA0);
  GLOAD16(sB1,      dB10);
  GLOAD16(sB1 + 16, dB10 + 2048);
  __syncthreads();

#pragma unroll 2
  for (int kt = 0; kt < 64; ++kt){
    const int cur = kt & 1;
    if (kt < 63){
      const unsigned short* nA = sA  + (kt + 1) * 32;
      const unsigned short* nB = sB1 + (kt + 1) * 32;
      GLOAD16(nA,      dA0  + (cur ^ 1) * 6144);
      GLOAD16(nB,      dB10 + (cur ^ 1) * 6144);
      GLOAD16(nB + 16, dB10 + (cur ^ 1) * 6144 + 2048);
    }
    const unsigned short* la = &lds[cur][0];
    const unsigned short* lb = &lds[cur][2048];
    bf16x8 af[2], bq[4];
#pragma unroll
    for (int j = 0; j < 2; ++j) af[j] = *(const bf16x8*)(la + g * 512 + (wn * 32 + j * 16 + cl) * 8);
#pragma unroll
    for (int i = 0; i < 4; ++i) bq[i] = *(const bf16x8*)(lb + g * 1024 + (wm * 64 + i * 16 + cl) * 8);
#pragma unroll
    for (int j = 0; j < 2; ++j)
#pragma unroll
      for (int i = 0; i < 4; ++i)
        acc[j][i] = __builtin_amdgcn_mfma_f32_16x16x32_bf16(af[j], bq[i], acc[j][i], 0, 0, 0);
    __syncthreads();
  }
#pragma unroll
  for (int j = 0; j < 2; ++j)
#pragma unroll
    for (int i = 0; i < 4; ++i){
      int m = m0 + wm * 64 + 16 * i + cl;
      int n = n0 + wn * 32 + 16 * j + 4 * g;
      *reinterpret_cast<f32x4*>(outp + (size_t)m * 1024 + n) = acc[j][i];
    }
}

// ---------------- stats: LDS-staged Q, two-pass FULL max, s split over 4 --------
__global__ __launch_bounds__(256, 4) void k_stats(const unsigned short* __restrict__ Qb,
                                                  const unsigned short* __restrict__ Kb,
                                                  float* __restrict__ mp,
                                                  float* __restrict__ lp){
  __shared__ __align__(16) unsigned short Qs[2][64][64];
  const int B = blockIdx.x;
  const int xcd = B & 7, rest = B >> 3;
  const int tx = rest & 7, gi = rest >> 3;
  const int grp = xcd + 8 * gi;
  const int bh = grp & 31, z = grp >> 5;
  const int b = bh >> 4, h = bh & 15;
  const int w = threadIdx.x >> 6, lane = threadIdx.x & 63;
  const int g = lane >> 4, cl = lane & 15;
  const int t0 = tx * 256 + w * 64;

  const unsigned short* kp = Kb + (size_t)(b * 2048 + t0 + cl) * 1024 + h * 64 + g * 8;
  bf16x8 a[4][2];
#pragma unroll
  for (int ti = 0; ti < 4; ++ti){
    a[ti][0] = *(const bf16x8*)(kp + (size_t)ti * 16 * 1024);
    a[ti][1] = *(const bf16x8*)(kp + (size_t)ti * 16 * 1024 + 32);
  }

  const int r0 = threadIdx.x >> 3, sl = threadIdx.x & 7;
  const unsigned short* qsrc = Qb + (size_t)(b * 2048 + z * 512 + r0) * 1024 + h * 64
                               + ((sl ^ (r0 & 7)) * 8);
  unsigned short* qdst0 = &Qs[0][0][0] + threadIdx.x * 8;

  const int e0 = (g ^ (cl & 7)) * 8;
  const int e1 = ((g + 4) ^ (cl & 7)) * 8;

  float m[16], l[16];
#pragma unroll
  for (int i = 0; i < 16; ++i){ m[i] = -3.0e38f; l[i] = 0.f; }

  // ---- pass 1: max ----
  GLOAD16(qsrc,             qdst0);
  GLOAD16(qsrc + 32 * 1024, qdst0 + 2048);
  __syncthreads();
  for (int c = 0; c < 8; ++c){
    const int buf = c & 1;
    if (c < 7){
      const unsigned short* s2 = qsrc + (size_t)(c + 1) * 64 * 1024;
      unsigned short* d2 = qdst0 + (buf ^ 1) * 4096;
      GLOAD16(s2,             d2);
      GLOAD16(s2 + 32 * 1024, d2 + 2048);
    }
#pragma unroll
    for (int st = 0; st < 4; ++st){
      const unsigned short* qrow = &Qs[buf][st * 16 + cl][0];
      bf16x8 b0 = *(const bf16x8*)(qrow + e0);
      bf16x8 b1 = *(const bf16x8*)(qrow + e1);
#pragma unroll
      for (int ti = 0; ti < 4; ++ti){
        f32x4 zz = {0.f, 0.f, 0.f, 0.f};
        f32x4 d = __builtin_amdgcn_mfma_f32_16x16x32_bf16(a[ti][0], b0, zz, 0, 0, 0);
        d = __builtin_amdgcn_mfma_f32_16x16x32_bf16(a[ti][1], b1, d, 0, 0, 0);
#pragma unroll
        for (int j = 0; j < 4; ++j) m[ti * 4 + j] = fmaxf(m[ti * 4 + j], d[j]);
      }
    }
    __syncthreads();
  }
#pragma unroll
  for (int off = 1; off < 16; off <<= 1)
#pragma unroll
    for (int i = 0; i < 16; ++i) m[i] = fmaxf(m[i], __shfl_xor(m[i], off));

  // ---- pass 2: sum of 2^(d-m) (zero-C, explicit subtract) ----
  GLOAD16(qsrc,             qdst0);
  GLOAD16(qsrc + 32 * 1024, qdst0 + 2048);
  __syncthreads();
  for (int c = 0; c < 8; ++c){
    const int buf = c & 1;
    if (c < 7){
      const unsigned short* s2 = qsrc + (size_t)(c + 1) * 64 * 1024;
      unsigned short* d2 = qdst0 + (buf ^ 1) * 4096;
      GLOAD16(s2,             d2);
      GLOAD16(s2 + 32 * 1024, d2 + 2048);
    }
#pragma unroll
    for (int st = 0; st < 4; ++st){
      const unsigned short* qrow = &Qs[buf][st * 16 + cl][0];
      bf16x8 b0 = *(const bf16x8*)(qrow + e0);
      bf16x8 b1 = *(const bf16x8*)(qrow + e1);
#pragma unroll
      for (int ti = 0; ti < 4; ++ti){
        f32x4 zz = {0.f, 0.f, 0.f, 0.f};
        f32x4 d = __builtin_amdgcn_mfma_f32_16x16x32_bf16(a[ti][0], b0, zz, 0, 0, 0);
        d = __builtin_amdgcn_mfma_f32_16x16x32_bf16(a[ti][1], b1, d, 0, 0, 0);
#pragma unroll
        for (int j = 0; j < 4; ++j) l[ti * 4 + j] += exp2f(d[j] - m[ti * 4 + j]);
      }
    }
    __syncthreads();
  }
#pragma unroll
  for (int off = 1; off < 16; off <<= 1)
#pragma unroll
    for (int i = 0; i < 16; ++i) l[i] += __shfl_xor(l[i], off);

  if (cl == 0){
    size_t base = ((size_t)z * 32 + bh) * 2048 + t0;
#pragma unroll
    for (int ti = 0; ti < 4; ++ti){
      f32x4 mv = {m[ti * 4 + 0], m[ti * 4 + 1], m[ti * 4 + 2], m[ti * 4 + 3]};
      f32x4 lv = {l[ti * 4 + 0], l[ti * 4 + 1], l[ti * 4 + 2], l[ti * 4 + 3]};
      *(f32x4*)(mp + base + ti * 16 + 4 * g) = mv;
      *(f32x4*)(lp + base + ti * 16 + 4 * g) = lv;
    }
  }
}

// ---------------- attention: 64-key chunks, P in registers, inline ms combine --
// grid 1024 flat (3|4|3 bits = xcd|sx|gi): 16 sx x (32 bh x 2 z).
__global__ __launch_bounds__(256, 4) void k_attn(const unsigned short* __restrict__ Qb,
                                                 const unsigned short* __restrict__ Kb,
                                                 const unsigned short* __restrict__ Vt,
                                                 const float* __restrict__ mp,
                                                 const float* __restrict__ lp,
                                                 unsigned short* __restrict__ Hd){
  __shared__ __align__(16) unsigned short KsL[2 * 64 * 64];  // 16 KB: [key][e]
  __shared__ __align__(16) unsigned short VsL[2 * 64 * 64];  // 16 KB: [e][t-chunk]
  __shared__ __align__(16) float Ms[1024];                   //  4 KB: -(m+log2 l)
  const int B = blockIdx.x;
  const int xcd = B & 7, rest = B >> 3;
  const int sx = rest & 15, gi = rest >> 4;         // gi 0..7
  const int grp = xcd + 8 * gi;                     // 0..63 = bh + 32*z
  const int bh = grp & 31, z = grp >> 5;            // z 0..1
  const int b = bh >> 4, h = bh & 15;
  const int lane = threadIdx.x & 63;
  const int g = lane >> 4, cl = lane & 15;
  const int s0w = sx * 128 + (threadIdx.x >> 6) * 32;
  const int tbase = z * 1024;

  // inline k_mcomb: combine 4 s-quarter partials for this block's 1024 t-slice
  // (identical fmax/exp2/log2 tree as the old k_mcomb kernel), store -ms in LDS
  {
    size_t base = (size_t)bh * 2048 + tbase + threadIdx.x * 4;
    f32x4 m0v = *(const f32x4*)(mp + base);
    f32x4 m1v = *(const f32x4*)(mp + base + 65536);
    f32x4 m2v = *(const f32x4*)(mp + base + 131072);
    f32x4 m3v = *(const f32x4*)(mp + base + 196608);
    f32x4 l0v = *(const f32x4*)(lp + base);
    f32x4 l1v = *(const f32x4*)(lp + base + 65536);
    f32x4 l2v = *(const f32x4*)(lp + base + 131072);
    f32x4 l3v = *(const f32x4*)(lp + base + 196608);
    f32x4 msv;
#pragma unroll
    for (int j = 0; j < 4; ++j){
      float m = fmaxf(fmaxf(m0v[j], m1v[j]), fmaxf(m2v[j], m3v[j]));
      float l = l0v[j] * exp2f(m0v[j] - m) + l1v[j] * exp2f(m1v[j] - m)
              + l2v[j] * exp2f(m2v[j] - m) + l3v[j] * exp2f(m3v[j] - m);
      msv[j] = -(m + log2f(l));
    }
    *(f32x4*)&Ms[threadIdx.x * 4] = msv;
  }

  bf16x8 q[2][2];
#pragma unroll
  for (int ss = 0; ss < 2; ++ss){
    const unsigned short* qp = Qb + (size_t)(b * 2048 + s0w + ss * 16 + cl) * 1024 + h * 64 + g * 8;
    q[ss][0] = *(const bf16x8*)(qp);
    q[ss][1] = *(const bf16x8*)(qp + 32);
  }
  f32x4 acc[4][2];
#pragma unroll
  for (int i = 0; i < 4; ++i)
#pragma unroll
    for (int ss = 0; ss < 2; ++ss) acc[i][ss] = f32x4{0.f, 0.f, 0.f, 0.f};

  const int srow = threadIdx.x >> 3;
  const int sseg = ((threadIdx.x & 7) ^ (srow & 7)) * 8;
  const unsigned short* kStage = Kb + (size_t)(b * 2048 + tbase + srow) * 1024 + h * 64 + sseg;
  const unsigned short* vStage = Vt + (size_t)(b * 1024 + h * 64 + srow) * 2048 + tbase + sseg;
  unsigned short* kDst = &KsL[0] + threadIdx.x * 8;
  unsigned short* vDst = &VsL[0] + threadIdx.x * 8;

  const int eK = (g ^ (cl & 7)) * 8;
  const int eK2 = ((g + 4) ^ (cl & 7)) * 8;

#define ASTAGE(c, buf) {                                                          \
    const unsigned short* ks_ = kStage + (size_t)(c) * 64 * 1024;                 \
    const unsigned short* vs_ = vStage + (c) * 64;                                \
    unsigned short* kd_ = kDst + (buf) * 4096;                                    \
    unsigned short* vd_ = vDst + (buf) * 4096;                                    \
    GLOAD16(ks_,             kd_);                                                \
    GLOAD16(ks_ + 32 * 1024, kd_ + 2048);                                         \
    GLOAD16(vs_,             vd_);                                                \
    GLOAD16(vs_ + (size_t)32 * 2048, vd_ + 2048); }

  ASTAGE(0, 0);
  __syncthreads();

  for (int c = 0; c < 16; ++c){
    const int buf = c & 1;
    if (c < 15) ASTAGE(c + 1, buf ^ 1);
    const unsigned short* Kbuf = &KsL[0] + buf * 4096;
    const unsigned short* Vbuf = &VsL[0] + buf * 4096;
#pragma unroll
    for (int sc = 0; sc < 2; ++sc){
      const unsigned short* kr0 = Kbuf + (sc * 32 + cl) * 64;
      const unsigned short* kr1 = Kbuf + (sc * 32 + 16 + cl) * 64;
      bf16x8 a00 = *(const bf16x8*)(kr0 + eK);
      bf16x8 a01 = *(const bf16x8*)(kr0 + eK2);
      bf16x8 a10 = *(const bf16x8*)(kr1 + eK);
      bf16x8 a11 = *(const bf16x8*)(kr1 + eK2);
      f32x4 ci0 = *(const f32x4*)&Ms[c * 64 + sc * 32 + 4 * g];        // = -ms
      f32x4 ci1 = *(const f32x4*)&Ms[c * 64 + sc * 32 + 16 + 4 * g];   // = -ms

      bf16x8 pb[2];
#pragma unroll
      for (int ss = 0; ss < 2; ++ss){
        __builtin_amdgcn_s_setprio(1);
        f32x4 d0 = __builtin_amdgcn_mfma_f32_16x16x32_bf16(a00, q[ss][0], ci0, 0, 0, 0);
        d0 = __builtin_amdgcn_mfma_f32_16x16x32_bf16(a01, q[ss][1], d0, 0, 0, 0);
        f32x4 d1 = __builtin_amdgcn_mfma_f32_16x16x32_bf16(a10, q[ss][0], ci1, 0, 0, 0);
        d1 = __builtin_amdgcn_mfma_f32_16x16x32_bf16(a11, q[ss][1], d1, 0, 0, 0);
        __builtin_amdgcn_s_setprio(0);
        unsigned w00 = pk2(exp2f(d0[0]), exp2f(d0[1]));
        unsigned w01 = pk2(exp2f(d0[2]), exp2f(d0[3]));
        unsigned w10 = pk2(exp2f(d1[0]), exp2f(d1[1]));
        unsigned w11 = pk2(exp2f(d1[2]), exp2f(d1[3]));
        unsigned sa0, sb0, sa1, sb1, W0, W1, W2, W3;
        swap32(w00, w10, sa0, sb0);
        swap32(w01, w11, sa1, sb1);
        swap16(sa0, sb0, W0, W2);
        swap16(sa1, sb1, W1, W3);
        union { unsigned u[4]; bf16x8 v; } fr;
        fr.u[0] = W0; fr.u[1] = W1; fr.u[2] = W2; fr.u[3] = W3;
        pb[ss] = fr.v;
      }
      __builtin_amdgcn_s_setprio(1);
#pragma unroll
      for (int i = 0; i < 4; ++i){
        bf16x8 av = *(const bf16x8*)(Vbuf + (16 * i + cl) * 64 + ((sc * 4 + g) ^ (cl & 7)) * 8);
        acc[i][0] = __builtin_amdgcn_mfma_f32_16x16x32_bf16(av, pb[0], acc[i][0], 0, 0, 0);
        acc[i][1] = __builtin_amdgcn_mfma_f32_16x16x32_bf16(av, pb[1], acc[i][1], 0, 0, 0);
      }
      __builtin_amdgcn_s_setprio(0);
    }
    __syncthreads();
  }
#undef ASTAGE
#pragma unroll
  for (int i = 0; i < 4; ++i)
#pragma unroll
    for (int ss = 0; ss < 2; ++ss){
      *reinterpret_cast<unsigned long long*>(
          Hd + (size_t)(b * 2048 + s0w + ss * 16 + cl) * 2048 + z * 1024 + h * 64 + 16 * i + 4 * g) =
          pack4(acc[i][ss][0], acc[i][ss][1], acc[i][ss][2], acc[i][ss][3]);
    }
}

extern "C" void kernel_launch(void* const* d_in, const int* in_sizes, int n_in,
                              void* d_out, int out_size, void* d_ws, size_t ws_size,
                              hipStream_t stream) {
  const float* x    = (const float*)d_in[0];
  const float* wq   = (const float*)d_in[2];
  const float* wk   = (const float*)d_in[3];
  const float* wv   = (const float*)d_in[4];
  const float* wagg = (const float*)d_in[5];
  float* outp = (float*)d_out;

  char* ws = (char*)d_ws;
  unsigned short* Xb  = (unsigned short*)(ws);                 // 8MB, dead after k_proj
  unsigned short* Hd  = (unsigned short*)(ws);                 // 16MB [4096][2048]
  unsigned short* Wall= (unsigned short*)(ws + 16777216);      // 6MB, dead after k_proj
  float* mp = (float*)(ws + 16777216);                         // 1 MB [4][32][2048]
  float* lp = (float*)(ws + 17825792);                         // 1 MB
  unsigned short* Wat = (unsigned short*)(ws + 23068672);      // 4 MB [d][2048]
  unsigned short* Qb  = (unsigned short*)(ws + 27262976);      // 8 MB (pre-scaled by C1)
  unsigned short* Kb  = (unsigned short*)(ws + 35651584);      // 8 MB
  unsigned short* Vt  = (unsigned short*)(ws + 44040192);      // 8 MB [b*1024+he][s]

  k_prep<<<dim3(5120), dim3(256), 0, stream>>>(x, wq, wk, wv, wagg, Xb, Wall, Wat);

  k_proj<<<dim3(8, 32, 3), dim3(256), 0, stream>>>(Wall, Xb, Qb, Kb, Vt);

  k_stats<<<dim3(1024), dim3(256), 0, stream>>>(Qb, Kb, mp, lp);

  k_attn<<<dim3(1024), dim3(256), 0, stream>>>(Qb, Kb, Vt, mp, lp, Hd);
  k_agg <<<dim3(16, 32), dim3(256), 0, stream>>>(Wat, Hd, outp);
}